// Round 1
// baseline (490.919 us; speedup 1.0000x reference)
//
#include <hip/hip_runtime.h>
#include <hip/hip_bf16.h>

typedef unsigned short u16;
typedef __attribute__((ext_vector_type(8))) short short8;
typedef __attribute__((ext_vector_type(4))) float float4v;

#define B_DIM 64
#define H_DIM 2048
#define K_DIM 256
#define M_KB  16384   // K_DIM * B_DIM

// workspace layout (bytes)
#define WS_WBF   0ull                       // 2048*2048*2 = 8388608
#define WS_AQ    (8388608ull)               // 128*2048*2  = 524288 (input rows 0-63, zeros 64-127)
#define WS_Q     (WS_AQ + 524288ull)        // 64*2048*4   = 524288
#define WS_KN2   (WS_Q + 524288ull)         // 16384*4
#define WS_DOTS  (WS_KN2 + 65536ull)        // 16384*4
#define WS_ATTN  (WS_DOTS + 65536ull)       // 16384*4

__device__ __forceinline__ u16 f2bf(float f) {
    unsigned int u = __float_as_uint(f);
    unsigned int r = (u + 0x7fffu + ((u >> 16) & 1u)) >> 16;
    return (u16)r;
}

__device__ __forceinline__ unsigned long long pack4(float4v v) {
    unsigned long long a0 = f2bf(v.x), a1 = f2bf(v.y), a2 = f2bf(v.z), a3 = f2bf(v.w);
    return a0 | (a1 << 16) | (a2 << 32) | (a3 << 48);
}

// async global->LDS 16B per lane; lds dest = wave-uniform base + lane*16
__device__ __forceinline__ void llds16(const u16* g, u16* l) {
    __builtin_amdgcn_global_load_lds(
        (__attribute__((address_space(1))) void*)g,
        (__attribute__((address_space(3))) void*)l, 16, 0, 0);
}

// ---------------- prep kernels ----------------
__global__ __launch_bounds__(256) void conv_w(const float* __restrict__ W, u16* __restrict__ Wb) {
    int t = blockIdx.x * 256 + threadIdx.x;      // 524288 threads, 8 elems each
    const float4v* src = (const float4v*)W;
    float4v a = src[t * 2], b = src[t * 2 + 1];
    unsigned long long lo = pack4(a), hi = pack4(b);
    unsigned long long* dst = (unsigned long long*)Wb;
    dst[t * 2] = lo;
    dst[t * 2 + 1] = hi;
}

__global__ __launch_bounds__(256) void prep_small(const float* __restrict__ in,
                                                  const float* __restrict__ bias,
                                                  u16* __restrict__ Aq, float* __restrict__ q,
                                                  float* __restrict__ kn2, float* __restrict__ dots) {
    int gid = blockIdx.x * 256 + threadIdx.x;
    int stride = gridDim.x * 256;
    for (int i = gid; i < 128 * H_DIM; i += stride)
        Aq[i] = (i < B_DIM * H_DIM) ? f2bf(in[i]) : (u16)0;
    for (int i = gid; i < B_DIM * H_DIM; i += stride)
        q[i] = bias[i & (H_DIM - 1)];
    for (int i = gid; i < M_KB; i += stride) { kn2[i] = 0.f; dots[i] = 0.f; }
}

// ---------------- GEMM (MODE 0: q = in @ W^T, split-K atomics; MODE 1: kb @ W^T fused norm/dot) ----
template <int MODE>
__global__ __launch_bounds__(256) void gemm_kernel(
        const float* __restrict__ A32,   // MODE1: kb fp32 [16384][2048]
        const u16* __restrict__ Abf,     // MODE0: in_bf16 [128][2048]
        const u16* __restrict__ Wb,      // [2048][2048] bf16, row-major [n][k]
        const float* __restrict__ bias,
        const float* __restrict__ q,     // MODE1 reads
        float* __restrict__ qout,        // MODE0 atomic dest
        float* __restrict__ kn2, float* __restrict__ dots) {
    __shared__ __align__(16) u16 As[128 * 32];
    __shared__ __align__(16) u16 Bs[128 * 32];

    const int tid = threadIdx.x;
    const int wave = tid >> 6, lane = tid & 63;
    const int l15 = lane & 15, qd = lane >> 4;
    const int wm = wave >> 1, wn = wave & 1;

    int mt, nt, k_begin, k_iters;
    if (MODE == 0) {
        nt = blockIdx.x & 15; mt = 0;
        k_begin = (blockIdx.x >> 4) * 512; k_iters = 16;
    } else {
        mt = blockIdx.x >> 4; nt = blockIdx.x & 15;
        k_begin = 0; k_iters = 64;
    }
    const int m0 = mt * 128, n0 = nt * 128;

    float4v acc[4][4] = {};

    const int srow = tid >> 3;          // 0..31 (A fp32 staging)
    const int scol = (tid & 7) * 4;     // 0..28
    const int grow = lane >> 2;         // 0..15 within 16-row chunk (lds-direct staging)
    const int gcol = (lane & 3) * 8;    // bf16 elems

    for (int kk = 0; kk < k_iters; ++kk) {
        const int k0 = k_begin + kk * 32;
        // B tile: W rows n0..n0+127, via global_load_lds (2 chunks of 16 rows per wave)
        #pragma unroll
        for (int i = 0; i < 2; ++i) {
            const int r = wave * 32 + i * 16;
            llds16(Wb + (size_t)(n0 + r + grow) * H_DIM + k0 + gcol, &Bs[r * 32]);
        }
        if (MODE == 0) {
            #pragma unroll
            for (int i = 0; i < 2; ++i) {
                const int r = wave * 32 + i * 16;
                llds16(Abf + (size_t)(r + grow) * H_DIM + k0 + gcol, &As[r * 32]);
            }
        } else {
            float4v va[4];
            #pragma unroll
            for (int r4 = 0; r4 < 4; ++r4)
                va[r4] = *(const float4v*)&A32[(size_t)(m0 + r4 * 32 + srow) * H_DIM + k0 + scol];
            #pragma unroll
            for (int r4 = 0; r4 < 4; ++r4)
                *(unsigned long long*)&As[(r4 * 32 + srow) * 32 + scol] = pack4(va[r4]);
        }
        __syncthreads();

        short8 af[4], bf_[4];
        #pragma unroll
        for (int mi = 0; mi < 4; ++mi)
            af[mi] = *(const short8*)&As[(wm * 64 + mi * 16 + l15) * 32 + qd * 8];
        #pragma unroll
        for (int ni = 0; ni < 4; ++ni)
            bf_[ni] = *(const short8*)&Bs[(wn * 64 + ni * 16 + l15) * 32 + qd * 8];
        #pragma unroll
        for (int mi = 0; mi < 4; ++mi)
            #pragma unroll
            for (int ni = 0; ni < 4; ++ni)
                acc[mi][ni] = __builtin_amdgcn_mfma_f32_16x16x32_bf16(af[mi], bf_[ni], acc[mi][ni], 0, 0, 0);
        __syncthreads();
    }

    const int n0w = n0 + wn * 64;
    if (MODE == 0) {
        if (wm == 0) {
            #pragma unroll
            for (int mi = 0; mi < 4; ++mi)
                #pragma unroll
                for (int reg = 0; reg < 4; ++reg) {
                    const int m = mi * 16 + qd * 4 + reg;   // 0..63 == b
                    #pragma unroll
                    for (int ni = 0; ni < 4; ++ni) {
                        const int n = n0w + ni * 16 + l15;
                        atomicAdd(&qout[m * H_DIM + n], acc[mi][ni][reg]);
                    }
                }
        }
    } else {
        float bv[4];
        #pragma unroll
        for (int ni = 0; ni < 4; ++ni) bv[ni] = bias[n0w + ni * 16 + l15];
        #pragma unroll
        for (int mi = 0; mi < 4; ++mi)
            #pragma unroll
            for (int reg = 0; reg < 4; ++reg) {
                const int mloc = mi * 16 + qd * 4 + reg;     // 0..63; b index = mloc
                const int mg = m0 + wm * 64 + mloc;
                const float* qrow = q + mloc * H_DIM;
                float s2 = 0.f, sd = 0.f;
                #pragma unroll
                for (int ni = 0; ni < 4; ++ni) {
                    const float y = acc[mi][ni][reg] + bv[ni];
                    const float qv = qrow[n0w + ni * 16 + l15];
                    s2 += y * y; sd += y * qv;
                }
                #pragma unroll
                for (int off = 1; off < 16; off <<= 1) {
                    s2 += __shfl_xor(s2, off);
                    sd += __shfl_xor(sd, off);
                }
                if (l15 == 0) {
                    atomicAdd(&kn2[mg], s2);
                    atomicAdd(&dots[mg], sd);
                }
            }
    }
}

// ---------------- softmax over K per b ----------------
__device__ __forceinline__ float blk_sum(float v, float* buf, int tid) {
    #pragma unroll
    for (int o = 32; o >= 1; o >>= 1) v += __shfl_xor(v, o);
    if ((tid & 63) == 0) buf[tid >> 6] = v;
    __syncthreads();
    float r = buf[0] + buf[1] + buf[2] + buf[3];
    __syncthreads();
    return r;
}
__device__ __forceinline__ float blk_max(float v, float* buf, int tid) {
    #pragma unroll
    for (int o = 32; o >= 1; o >>= 1) v = fmaxf(v, __shfl_xor(v, o));
    if ((tid & 63) == 0) buf[tid >> 6] = v;
    __syncthreads();
    float r = fmaxf(fmaxf(buf[0], buf[1]), fmaxf(buf[2], buf[3]));
    __syncthreads();
    return r;
}

__global__ __launch_bounds__(256) void softmax_kernel(const float* __restrict__ q,
                                                      const float* __restrict__ kn2,
                                                      const float* __restrict__ dots,
                                                      float* __restrict__ attn) {
    __shared__ float buf[4];
    const int b = blockIdx.x, tid = threadIdx.x;
    float s = 0.f;
    #pragma unroll
    for (int i = 0; i < 8; ++i) {
        float v = q[b * H_DIM + i * 256 + tid];
        s += v * v;
    }
    const float qn = fmaxf(sqrtf(blk_sum(s, buf, tid)), 1e-8f);
    const int k = tid;   // K == 256 == blockDim
    const float kn = fmaxf(sqrtf(kn2[k * B_DIM + b]), 1e-8f);
    const float sc = dots[k * B_DIM + b] / (qn * kn);
    const float mx = blk_max(sc, buf, tid);
    const float e = expf(sc - mx);
    const float se = blk_sum(e, buf, tid);
    attn[k * B_DIM + b] = e / se;
}

// ---------------- output: out = input + sum_k attn[k,b]*kb[k,b,:] ----------------
__global__ __launch_bounds__(256) void output_kernel(const float* __restrict__ input,
                                                     const float* __restrict__ kb,
                                                     const float* __restrict__ attn,
                                                     float* __restrict__ out) {
    __shared__ float a_s[K_DIM];
    const int b = blockIdx.y, hc = blockIdx.x, tid = threadIdx.x;
    a_s[tid] = attn[tid * B_DIM + b];
    __syncthreads();
    const int h = hc * 256 + tid;
    const float* base = kb + (size_t)b * H_DIM + h;
    float s = 0.f;
    #pragma unroll 4
    for (int k = 0; k < K_DIM; ++k)
        s += a_s[k] * base[(size_t)k * (B_DIM * H_DIM)];
    out[b * H_DIM + h] = input[b * H_DIM + h] + s;
}

extern "C" void kernel_launch(void* const* d_in, const int* in_sizes, int n_in,
                              void* d_out, int out_size, void* d_ws, size_t ws_size,
                              hipStream_t stream) {
    const float* input = (const float*)d_in[0];
    const float* kb    = (const float*)d_in[1];
    const float* W     = (const float*)d_in[2];
    const float* bias  = (const float*)d_in[3];
    float* out = (float*)d_out;
    char* ws = (char*)d_ws;

    u16*   Wb   = (u16*)(ws + WS_WBF);
    u16*   Aq   = (u16*)(ws + WS_AQ);
    float* q    = (float*)(ws + WS_Q);
    float* kn2  = (float*)(ws + WS_KN2);
    float* dots = (float*)(ws + WS_DOTS);
    float* attn = (float*)(ws + WS_ATTN);

    conv_w<<<2048, 256, 0, stream>>>(W, Wb);
    prep_small<<<256, 256, 0, stream>>>(input, bias, Aq, q, kn2, dots);
    gemm_kernel<0><<<64, 256, 0, stream>>>(nullptr, Aq, Wb, bias, nullptr, q, nullptr, nullptr);
    gemm_kernel<1><<<2048, 256, 0, stream>>>(kb, nullptr, Wb, bias, q, nullptr, kn2, dots);
    softmax_kernel<<<64, 256, 0, stream>>>(q, kn2, dots, attn);
    output_kernel<<<dim3(8, 64), 256, 0, stream>>>(input, kb, attn, out);
}

// Round 2
// 431.314 us; speedup vs baseline: 1.1382x; 1.1382x over previous
//
#include <hip/hip_runtime.h>
#include <hip/hip_bf16.h>

typedef unsigned short u16;
typedef __attribute__((ext_vector_type(8))) short short8;
typedef __attribute__((ext_vector_type(4))) float float4v;

#define B_DIM 64
#define H_DIM 2048
#define K_DIM 256
#define M_KB  16384   // K_DIM * B_DIM

// workspace layout (bytes)
#define WS_WBF   0ull                       // 2048*2048*2 = 8388608
#define WS_AQ    (8388608ull)               // 128*2048*2  = 524288 (input rows 0-63, zeros 64-127)
#define WS_Q     (WS_AQ + 524288ull)        // 64*2048*4   = 524288
#define WS_KN2   (WS_Q + 524288ull)         // 16384*4
#define WS_DOTS  (WS_KN2 + 65536ull)        // 16384*4
#define WS_ATTN  (WS_DOTS + 65536ull)       // 16384*4
#define WS_KBF   (WS_ATTN + 65536ull)       // 16384*2048*2 = 67108864
#define WS_NEEDED (WS_KBF + 67108864ull)

__device__ __forceinline__ u16 f2bf(float f) {
    unsigned int u = __float_as_uint(f);
    unsigned int r = (u + 0x7fffu + ((u >> 16) & 1u)) >> 16;
    return (u16)r;
}

__device__ __forceinline__ unsigned long long pack4(float4v v) {
    unsigned long long a0 = f2bf(v.x), a1 = f2bf(v.y), a2 = f2bf(v.z), a3 = f2bf(v.w);
    return a0 | (a1 << 16) | (a2 << 32) | (a3 << 48);
}

// async global->LDS 16B per lane; lds dest = wave-uniform base + lane*16
__device__ __forceinline__ void llds16(const u16* g, u16* l) {
    __builtin_amdgcn_global_load_lds(
        (__attribute__((address_space(1))) void*)g,
        (__attribute__((address_space(3))) void*)l, 16, 0, 0);
}

// ---------------- fp32 -> bf16 bulk convert (8 elems/thread) ----------------
__global__ __launch_bounds__(256) void conv_f2b(const float* __restrict__ src,
                                                u16* __restrict__ dst) {
    long long t = (long long)blockIdx.x * 256 + threadIdx.x;
    const float4v* s4 = (const float4v*)src;
    float4v a = s4[t * 2], b = s4[t * 2 + 1];
    unsigned long long* d8 = (unsigned long long*)dst;
    d8[t * 2] = pack4(a);
    d8[t * 2 + 1] = pack4(b);
}

__global__ __launch_bounds__(256) void prep_small(const float* __restrict__ in,
                                                  const float* __restrict__ bias,
                                                  u16* __restrict__ Aq, float* __restrict__ q,
                                                  float* __restrict__ kn2, float* __restrict__ dots) {
    int gid = blockIdx.x * 256 + threadIdx.x;
    int stride = gridDim.x * 256;
    for (int i = gid; i < 128 * H_DIM; i += stride)
        Aq[i] = (i < B_DIM * H_DIM) ? f2bf(in[i]) : (u16)0;
    for (int i = gid; i < B_DIM * H_DIM; i += stride)
        q[i] = bias[i & (H_DIM - 1)];
    for (int i = gid; i < M_KB; i += stride) { kn2[i] = 0.f; dots[i] = 0.f; }
}

// ---------------- GEMM ----------------
// MODE 0: q = in @ W^T  (bf16 A via llds16, split-K atomics onto qout)
// MODE 1: kb @ W^T, fp32 A staged through VGPRs (fallback if ws too small)
// MODE 2: kb @ W^T, bf16 A via llds16 (fast path)
template <int MODE>
__global__ __launch_bounds__(256) void gemm_kernel(
        const float* __restrict__ A32,   // MODE1: kb fp32 [16384][2048]
        const u16* __restrict__ Abf,     // MODE0/2: bf16 A rows
        const u16* __restrict__ Wb,      // [2048][2048] bf16, row-major [n][k]
        const float* __restrict__ bias,
        const float* __restrict__ q,     // MODE1/2 reads
        float* __restrict__ qout,        // MODE0 atomic dest
        float* __restrict__ kn2, float* __restrict__ dots) {
    __shared__ __align__(16) u16 As[128 * 32];
    __shared__ __align__(16) u16 Bs[128 * 32];

    const int tid = threadIdx.x;
    const int wave = tid >> 6, lane = tid & 63;
    const int l15 = lane & 15, qd = lane >> 4;
    const int wm = wave >> 1, wn = wave & 1;

    int mt, nt, k_begin, k_iters;
    if (MODE == 0) {
        nt = blockIdx.x & 15; mt = 0;
        k_begin = (blockIdx.x >> 4) * 512; k_iters = 16;
    } else {
        mt = blockIdx.x >> 4; nt = blockIdx.x & 15;
        k_begin = 0; k_iters = 64;
    }
    const int m0 = mt * 128, n0 = nt * 128;

    float4v acc[4][4] = {};

    const int srow = tid >> 3;          // 0..31 (A fp32 staging)
    const int scol = (tid & 7) * 4;     // 0..28
    const int grow = lane >> 2;         // 0..15 within 16-row chunk (lds-direct staging)
    const int gcol = (lane & 3) * 8;    // bf16 elems

    for (int kk = 0; kk < k_iters; ++kk) {
        const int k0 = k_begin + kk * 32;
        // B tile: W rows n0..n0+127, via global_load_lds (2 chunks of 16 rows per wave)
        #pragma unroll
        for (int i = 0; i < 2; ++i) {
            const int r = wave * 32 + i * 16;
            llds16(Wb + (size_t)(n0 + r + grow) * H_DIM + k0 + gcol, &Bs[r * 32]);
        }
        if (MODE == 1) {
            float4v va[4];
            #pragma unroll
            for (int r4 = 0; r4 < 4; ++r4)
                va[r4] = *(const float4v*)&A32[(size_t)(m0 + r4 * 32 + srow) * H_DIM + k0 + scol];
            #pragma unroll
            for (int r4 = 0; r4 < 4; ++r4)
                *(unsigned long long*)&As[(r4 * 32 + srow) * 32 + scol] = pack4(va[r4]);
        } else {
            #pragma unroll
            for (int i = 0; i < 2; ++i) {
                const int r = wave * 32 + i * 16;
                llds16(Abf + (size_t)(m0 + r + grow) * H_DIM + k0 + gcol, &As[r * 32]);
            }
        }
        __syncthreads();

        short8 af[4], bf_[4];
        #pragma unroll
        for (int mi = 0; mi < 4; ++mi)
            af[mi] = *(const short8*)&As[(wm * 64 + mi * 16 + l15) * 32 + qd * 8];
        #pragma unroll
        for (int ni = 0; ni < 4; ++ni)
            bf_[ni] = *(const short8*)&Bs[(wn * 64 + ni * 16 + l15) * 32 + qd * 8];
        #pragma unroll
        for (int mi = 0; mi < 4; ++mi)
            #pragma unroll
            for (int ni = 0; ni < 4; ++ni)
                acc[mi][ni] = __builtin_amdgcn_mfma_f32_16x16x32_bf16(af[mi], bf_[ni], acc[mi][ni], 0, 0, 0);
        __syncthreads();
    }

    const int n0w = n0 + wn * 64;
    if (MODE == 0) {
        if (wm == 0) {
            #pragma unroll
            for (int mi = 0; mi < 4; ++mi)
                #pragma unroll
                for (int reg = 0; reg < 4; ++reg) {
                    const int m = mi * 16 + qd * 4 + reg;   // 0..63 == b
                    #pragma unroll
                    for (int ni = 0; ni < 4; ++ni) {
                        const int n = n0w + ni * 16 + l15;
                        atomicAdd(&qout[m * H_DIM + n], acc[mi][ni][reg]);
                    }
                }
        }
    } else {
        float bv[4];
        #pragma unroll
        for (int ni = 0; ni < 4; ++ni) bv[ni] = bias[n0w + ni * 16 + l15];
        #pragma unroll
        for (int mi = 0; mi < 4; ++mi)
            #pragma unroll
            for (int reg = 0; reg < 4; ++reg) {
                const int mloc = mi * 16 + qd * 4 + reg;     // 0..63; b index = mloc
                const int mg = m0 + wm * 64 + mloc;
                const float* qrow = q + mloc * H_DIM;
                float s2 = 0.f, sd = 0.f;
                #pragma unroll
                for (int ni = 0; ni < 4; ++ni) {
                    const float y = acc[mi][ni][reg] + bv[ni];
                    const float qv = qrow[n0w + ni * 16 + l15];
                    s2 += y * y; sd += y * qv;
                }
                #pragma unroll
                for (int off = 1; off < 16; off <<= 1) {
                    s2 += __shfl_xor(s2, off);
                    sd += __shfl_xor(sd, off);
                }
                if (l15 == 0) {
                    atomicAdd(&kn2[mg], s2);
                    atomicAdd(&dots[mg], sd);
                }
            }
    }
}

// ---------------- softmax over K per b ----------------
__device__ __forceinline__ float blk_sum(float v, float* buf, int tid) {
    #pragma unroll
    for (int o = 32; o >= 1; o >>= 1) v += __shfl_xor(v, o);
    if ((tid & 63) == 0) buf[tid >> 6] = v;
    __syncthreads();
    float r = buf[0] + buf[1] + buf[2] + buf[3];
    __syncthreads();
    return r;
}
__device__ __forceinline__ float blk_max(float v, float* buf, int tid) {
    #pragma unroll
    for (int o = 32; o >= 1; o >>= 1) v = fmaxf(v, __shfl_xor(v, o));
    if ((tid & 63) == 0) buf[tid >> 6] = v;
    __syncthreads();
    float r = fmaxf(fmaxf(buf[0], buf[1]), fmaxf(buf[2], buf[3]));
    __syncthreads();
    return r;
}

__global__ __launch_bounds__(256) void softmax_kernel(const float* __restrict__ q,
                                                      const float* __restrict__ kn2,
                                                      const float* __restrict__ dots,
                                                      float* __restrict__ attn) {
    __shared__ float buf[4];
    const int b = blockIdx.x, tid = threadIdx.x;
    float s = 0.f;
    #pragma unroll
    for (int i = 0; i < 8; ++i) {
        float v = q[b * H_DIM + i * 256 + tid];
        s += v * v;
    }
    const float qn = fmaxf(sqrtf(blk_sum(s, buf, tid)), 1e-8f);
    const int k = tid;   // K == 256 == blockDim
    const float kn = fmaxf(sqrtf(kn2[k * B_DIM + b]), 1e-8f);
    const float sc = dots[k * B_DIM + b] / (qn * kn);
    const float mx = blk_max(sc, buf, tid);
    const float e = expf(sc - mx);
    const float se = blk_sum(e, buf, tid);
    attn[k * B_DIM + b] = e / se;
}

// ---------------- output: out = input + sum_k attn[k,b]*kb[k,b,:] ----------------
__global__ __launch_bounds__(256) void output_kernel(const float* __restrict__ input,
                                                     const float* __restrict__ kb,
                                                     const float* __restrict__ attn,
                                                     float* __restrict__ out) {
    __shared__ float a_s[K_DIM];
    const int b = blockIdx.y, hc = blockIdx.x, tid = threadIdx.x;
    a_s[tid] = attn[tid * B_DIM + b];
    __syncthreads();
    const int h = hc * 256 + tid;
    const float* base = kb + (size_t)b * H_DIM + h;
    float s = 0.f;
    #pragma unroll 4
    for (int k = 0; k < K_DIM; ++k)
        s += a_s[k] * base[(size_t)k * (B_DIM * H_DIM)];
    out[b * H_DIM + h] = input[b * H_DIM + h] + s;
}

extern "C" void kernel_launch(void* const* d_in, const int* in_sizes, int n_in,
                              void* d_out, int out_size, void* d_ws, size_t ws_size,
                              hipStream_t stream) {
    const float* input = (const float*)d_in[0];
    const float* kb    = (const float*)d_in[1];
    const float* W     = (const float*)d_in[2];
    const float* bias  = (const float*)d_in[3];
    float* out = (float*)d_out;
    char* ws = (char*)d_ws;

    u16*   Wb   = (u16*)(ws + WS_WBF);
    u16*   Aq   = (u16*)(ws + WS_AQ);
    float* q    = (float*)(ws + WS_Q);
    float* kn2  = (float*)(ws + WS_KN2);
    float* dots = (float*)(ws + WS_DOTS);
    float* attn = (float*)(ws + WS_ATTN);
    u16*   Kbf  = (u16*)(ws + WS_KBF);

    const bool fast = (ws_size >= WS_NEEDED);

    conv_f2b<<<2048, 256, 0, stream>>>(W, Wb);                 // 4.2M elems
    prep_small<<<256, 256, 0, stream>>>(input, bias, Aq, q, kn2, dots);
    gemm_kernel<0><<<64, 256, 0, stream>>>(nullptr, Aq, Wb, bias, nullptr, q, nullptr, nullptr);
    if (fast) {
        conv_f2b<<<16384, 256, 0, stream>>>(kb, Kbf);          // 33.5M elems
        gemm_kernel<2><<<2048, 256, 0, stream>>>(nullptr, Kbf, Wb, bias, q, nullptr, kn2, dots);
    } else {
        gemm_kernel<1><<<2048, 256, 0, stream>>>(kb, nullptr, Wb, bias, q, nullptr, kn2, dots);
    }
    softmax_kernel<<<64, 256, 0, stream>>>(q, kn2, dots, attn);
    output_kernel<<<dim3(8, 64), 256, 0, stream>>>(input, kb, attn, out);
}

// Round 3
// 415.361 us; speedup vs baseline: 1.1819x; 1.0384x over previous
//
#include <hip/hip_runtime.h>
#include <hip/hip_bf16.h>

typedef unsigned short u16;
typedef __attribute__((ext_vector_type(8))) short short8;
typedef __attribute__((ext_vector_type(4))) float float4v;

#define B_DIM 64
#define H_DIM 2048
#define K_DIM 256
#define M_KB  16384   // K_DIM * B_DIM

// workspace layout (bytes)
#define WS_WBF   0ull                       // 2048*2048*2 = 8388608
#define WS_AQ    (8388608ull)               // 128*2048*2  = 524288 (input rows 0-63, zeros 64-127)
#define WS_Q     (WS_AQ + 524288ull)        // 64*2048*4   = 524288
#define WS_KN2   (WS_Q + 524288ull)         // 16384*4
#define WS_DOTS  (WS_KN2 + 65536ull)        // 16384*4
#define WS_ATTN  (WS_DOTS + 65536ull)       // 16384*4
#define WS_KBF   (WS_ATTN + 65536ull)       // 16384*2048*2 = 67108864
#define WS_NEEDED (WS_KBF + 67108864ull)

__device__ __forceinline__ u16 f2bf(float f) {
    unsigned int u = __float_as_uint(f);
    unsigned int r = (u + 0x7fffu + ((u >> 16) & 1u)) >> 16;
    return (u16)r;
}

__device__ __forceinline__ unsigned long long pack4(float4v v) {
    unsigned long long a0 = f2bf(v.x), a1 = f2bf(v.y), a2 = f2bf(v.z), a3 = f2bf(v.w);
    return a0 | (a1 << 16) | (a2 << 32) | (a3 << 48);
}

// async global->LDS 16B per lane; lds dest = wave-uniform base + lane*16
__device__ __forceinline__ void llds16(const u16* g, u16* l) {
    __builtin_amdgcn_global_load_lds(
        (__attribute__((address_space(1))) void*)g,
        (__attribute__((address_space(3))) void*)l, 16, 0, 0);
}

// ---------------- fp32 -> bf16 bulk convert: 1 float4 load + 1 8B store/thread ----
__global__ __launch_bounds__(256) void conv_f2b(const float* __restrict__ src,
                                                u16* __restrict__ dst) {
    long long t = (long long)blockIdx.x * 256 + threadIdx.x;
    const float4v* s4 = (const float4v*)src;
    unsigned long long* d8 = (unsigned long long*)dst;
    d8[t] = pack4(s4[t]);
}

__global__ __launch_bounds__(256) void prep_small(const float* __restrict__ in,
                                                  const float* __restrict__ bias,
                                                  u16* __restrict__ Aq, float* __restrict__ q,
                                                  float* __restrict__ kn2, float* __restrict__ dots) {
    int gid = blockIdx.x * 256 + threadIdx.x;
    int stride = gridDim.x * 256;
    for (int i = gid; i < 128 * H_DIM; i += stride)
        Aq[i] = (i < B_DIM * H_DIM) ? f2bf(in[i]) : (u16)0;
    for (int i = gid; i < B_DIM * H_DIM; i += stride)
        q[i] = bias[i & (H_DIM - 1)];
    for (int i = gid; i < M_KB; i += stride) { kn2[i] = 0.f; dots[i] = 0.f; }
}

// ---------------- GEMM ----------------
// MODE 0: q = in @ W^T  (bf16 A via llds16, split-K atomics onto qout)
// MODE 1: kb @ W^T, fp32 A staged through VGPRs (fallback if ws too small)
// MODE 2: kb @ W^T, bf16 A via llds16 (fast path)
template <int MODE>
__global__ __launch_bounds__(256, 3) void gemm_kernel(
        const float* __restrict__ A32,   // MODE1: kb fp32 [16384][2048]
        const u16* __restrict__ Abf,     // MODE0/2: bf16 A rows
        const u16* __restrict__ Wb,      // [2048][2048] bf16, row-major [n][k]
        const float* __restrict__ bias,
        const float* __restrict__ q,     // MODE1/2 reads
        float* __restrict__ qout,        // MODE0 atomic dest
        float* __restrict__ kn2, float* __restrict__ dots) {
    __shared__ __align__(16) u16 As[128 * 32];
    __shared__ __align__(16) u16 Bs[128 * 32];

    const int tid = threadIdx.x;
    const int wave = tid >> 6, lane = tid & 63;
    const int l15 = lane & 15, qd = lane >> 4;
    const int wm = wave >> 1, wn = wave & 1;

    int mt, nt, k_begin, k_iters;
    if (MODE == 0) {
        nt = blockIdx.x & 15; mt = 0;
        k_begin = (blockIdx.x >> 4) * 512; k_iters = 16;
    } else {
        // swizzle: groups of 64 blocks cover 4 mt x 16 nt for L2 locality
        const int bx = blockIdx.x;
        mt = (bx >> 6) * 4 + (bx & 3);
        nt = (bx >> 2) & 15;
        k_begin = 0; k_iters = 64;
    }
    const int m0 = mt * 128, n0 = nt * 128;

    float4v acc[4][4] = {};

    const int srow = tid >> 3;          // 0..31 (A fp32 staging)
    const int scol = (tid & 7) * 4;     // 0..28
    const int grow = lane >> 2;         // 0..15 within 16-row chunk (lds-direct staging)
    const int gcol = (lane & 3) * 8;    // bf16 elems

    for (int kk = 0; kk < k_iters; ++kk) {
        const int k0 = k_begin + kk * 32;
        // B tile: W rows n0..n0+127, via global_load_lds (2 chunks of 16 rows per wave)
        #pragma unroll
        for (int i = 0; i < 2; ++i) {
            const int r = wave * 32 + i * 16;
            llds16(Wb + (size_t)(n0 + r + grow) * H_DIM + k0 + gcol, &Bs[r * 32]);
        }
        if (MODE == 1) {
            float4v va[4];
            #pragma unroll
            for (int r4 = 0; r4 < 4; ++r4)
                va[r4] = *(const float4v*)&A32[(size_t)(m0 + r4 * 32 + srow) * H_DIM + k0 + scol];
            #pragma unroll
            for (int r4 = 0; r4 < 4; ++r4)
                *(unsigned long long*)&As[(r4 * 32 + srow) * 32 + scol] = pack4(va[r4]);
        } else {
            #pragma unroll
            for (int i = 0; i < 2; ++i) {
                const int r = wave * 32 + i * 16;
                llds16(Abf + (size_t)(m0 + r + grow) * H_DIM + k0 + gcol, &As[r * 32]);
            }
        }
        __syncthreads();

        short8 af[4], bf_[4];
        #pragma unroll
        for (int mi = 0; mi < 4; ++mi)
            af[mi] = *(const short8*)&As[(wm * 64 + mi * 16 + l15) * 32 + qd * 8];
        #pragma unroll
        for (int ni = 0; ni < 4; ++ni)
            bf_[ni] = *(const short8*)&Bs[(wn * 64 + ni * 16 + l15) * 32 + qd * 8];
        #pragma unroll
        for (int mi = 0; mi < 4; ++mi)
            #pragma unroll
            for (int ni = 0; ni < 4; ++ni)
                acc[mi][ni] = __builtin_amdgcn_mfma_f32_16x16x32_bf16(af[mi], bf_[ni], acc[mi][ni], 0, 0, 0);
        __syncthreads();
    }

    const int n0w = n0 + wn * 64;
    if (MODE == 0) {
        if (wm == 0) {
            #pragma unroll
            for (int mi = 0; mi < 4; ++mi)
                #pragma unroll
                for (int reg = 0; reg < 4; ++reg) {
                    const int m = mi * 16 + qd * 4 + reg;   // 0..63 == b
                    #pragma unroll
                    for (int ni = 0; ni < 4; ++ni) {
                        const int n = n0w + ni * 16 + l15;
                        atomicAdd(&qout[m * H_DIM + n], acc[mi][ni][reg]);
                    }
                }
        }
    } else {
        float bv[4];
        #pragma unroll
        for (int ni = 0; ni < 4; ++ni) bv[ni] = bias[n0w + ni * 16 + l15];
        #pragma unroll
        for (int mi = 0; mi < 4; ++mi)
            #pragma unroll
            for (int reg = 0; reg < 4; ++reg) {
                const int mloc = mi * 16 + qd * 4 + reg;     // 0..63; b index = mloc
                const int mg = m0 + wm * 64 + mloc;
                const float* qrow = q + mloc * H_DIM;
                float s2 = 0.f, sd = 0.f;
                #pragma unroll
                for (int ni = 0; ni < 4; ++ni) {
                    const float y = acc[mi][ni][reg] + bv[ni];
                    const float qv = qrow[n0w + ni * 16 + l15];
                    s2 += y * y; sd += y * qv;
                }
                #pragma unroll
                for (int off = 1; off < 16; off <<= 1) {
                    s2 += __shfl_xor(s2, off);
                    sd += __shfl_xor(sd, off);
                }
                if (l15 == 0) {
                    atomicAdd(&kn2[mg], s2);
                    atomicAdd(&dots[mg], sd);
                }
            }
    }
}

// ---------------- softmax over K per b ----------------
__device__ __forceinline__ float blk_sum(float v, float* buf, int tid) {
    #pragma unroll
    for (int o = 32; o >= 1; o >>= 1) v += __shfl_xor(v, o);
    if ((tid & 63) == 0) buf[tid >> 6] = v;
    __syncthreads();
    float r = buf[0] + buf[1] + buf[2] + buf[3];
    __syncthreads();
    return r;
}
__device__ __forceinline__ float blk_max(float v, float* buf, int tid) {
    #pragma unroll
    for (int o = 32; o >= 1; o >>= 1) v = fmaxf(v, __shfl_xor(v, o));
    if ((tid & 63) == 0) buf[tid >> 6] = v;
    __syncthreads();
    float r = fmaxf(fmaxf(buf[0], buf[1]), fmaxf(buf[2], buf[3]));
    __syncthreads();
    return r;
}

__global__ __launch_bounds__(256) void softmax_kernel(const float* __restrict__ q,
                                                      const float* __restrict__ kn2,
                                                      const float* __restrict__ dots,
                                                      float* __restrict__ attn) {
    __shared__ float buf[4];
    const int b = blockIdx.x, tid = threadIdx.x;
    float s = 0.f;
    #pragma unroll
    for (int i = 0; i < 8; ++i) {
        float v = q[b * H_DIM + i * 256 + tid];
        s += v * v;
    }
    const float qn = fmaxf(sqrtf(blk_sum(s, buf, tid)), 1e-8f);
    const int k = tid;   // K == 256 == blockDim
    const float kn = fmaxf(sqrtf(kn2[k * B_DIM + b]), 1e-8f);
    const float sc = dots[k * B_DIM + b] / (qn * kn);
    const float mx = blk_max(sc, buf, tid);
    const float e = expf(sc - mx);
    const float se = blk_sum(e, buf, tid);
    attn[k * B_DIM + b] = e / se;
}

// ---------------- output (bf16 kb): out = input + sum_k attn[k,b]*kb[k,b,:] ----------------
__global__ __launch_bounds__(256) void output_kernel_bf(const float* __restrict__ input,
                                                        const u16* __restrict__ kbf,
                                                        const float* __restrict__ attn,
                                                        float* __restrict__ out) {
    __shared__ float a_s[K_DIM];
    const int b = blockIdx.y, hc = blockIdx.x, tid = threadIdx.x;
    a_s[tid] = attn[tid * B_DIM + b];
    __syncthreads();
    const int h2 = hc * 256 + tid;          // unit of 2 h elems
    const unsigned* base = (const unsigned*)kbf + ((size_t)b * H_DIM >> 1) + h2;
    float s0 = 0.f, s1 = 0.f;
    #pragma unroll 4
    for (int k = 0; k < K_DIM; ++k) {
        unsigned p = base[(size_t)k * (B_DIM * H_DIM / 2)];
        float v0 = __uint_as_float(p << 16);
        float v1 = __uint_as_float(p & 0xffff0000u);
        float a = a_s[k];
        s0 += a * v0; s1 += a * v1;
    }
    const int h = h2 * 2;
    float2 iv = *(const float2*)&input[(size_t)b * H_DIM + h];
    float2 r; r.x = iv.x + s0; r.y = iv.y + s1;
    *(float2*)&out[(size_t)b * H_DIM + h] = r;
}

// fp32 fallback
__global__ __launch_bounds__(256) void output_kernel(const float* __restrict__ input,
                                                     const float* __restrict__ kb,
                                                     const float* __restrict__ attn,
                                                     float* __restrict__ out) {
    __shared__ float a_s[K_DIM];
    const int b = blockIdx.y, hc = blockIdx.x, tid = threadIdx.x;
    a_s[tid] = attn[tid * B_DIM + b];
    __syncthreads();
    const int h = hc * 256 + tid;
    const float* base = kb + (size_t)b * H_DIM + h;
    float s = 0.f;
    #pragma unroll 4
    for (int k = 0; k < K_DIM; ++k)
        s += a_s[k] * base[(size_t)k * (B_DIM * H_DIM)];
    out[b * H_DIM + h] = input[b * H_DIM + h] + s;
}

extern "C" void kernel_launch(void* const* d_in, const int* in_sizes, int n_in,
                              void* d_out, int out_size, void* d_ws, size_t ws_size,
                              hipStream_t stream) {
    const float* input = (const float*)d_in[0];
    const float* kb    = (const float*)d_in[1];
    const float* W     = (const float*)d_in[2];
    const float* bias  = (const float*)d_in[3];
    float* out = (float*)d_out;
    char* ws = (char*)d_ws;

    u16*   Wb   = (u16*)(ws + WS_WBF);
    u16*   Aq   = (u16*)(ws + WS_AQ);
    float* q    = (float*)(ws + WS_Q);
    float* kn2  = (float*)(ws + WS_KN2);
    float* dots = (float*)(ws + WS_DOTS);
    float* attn = (float*)(ws + WS_ATTN);
    u16*   Kbf  = (u16*)(ws + WS_KBF);

    const bool fast = (ws_size >= WS_NEEDED);

    conv_f2b<<<4096, 256, 0, stream>>>(W, Wb);                 // 4.2M elems, 1 f4/thread
    prep_small<<<256, 256, 0, stream>>>(input, bias, Aq, q, kn2, dots);
    gemm_kernel<0><<<64, 256, 0, stream>>>(nullptr, Aq, Wb, bias, nullptr, q, nullptr, nullptr);
    if (fast) {
        conv_f2b<<<32768, 256, 0, stream>>>(kb, Kbf);          // 33.5M elems
        gemm_kernel<2><<<2048, 256, 0, stream>>>(nullptr, Kbf, Wb, bias, q, nullptr, kn2, dots);
        softmax_kernel<<<64, 256, 0, stream>>>(q, kn2, dots, attn);
        output_kernel_bf<<<dim3(4, 64), 256, 0, stream>>>(input, Kbf, attn, out);
    } else {
        gemm_kernel<1><<<2048, 256, 0, stream>>>(kb, nullptr, Wb, bias, q, nullptr, kn2, dots);
        softmax_kernel<<<64, 256, 0, stream>>>(q, kn2, dots, attn);
        output_kernel<<<dim3(8, 64), 256, 0, stream>>>(input, kb, attn, out);
    }
}